// Round 1
// baseline (145.267 us; speedup 1.0000x reference)
//
#include <hip/hip_runtime.h>

#define B_DIM 1024
#define C_DIM 256
#define ELL   9
#define E_DIM 10
#define K1    1
#define K2    4
#define K3    20

#define N_CUBIC 165            // C(9+2,3) monomials a<=b<=c
#define N_QUAD  45             // pairs a<=b
#define ROW3    80             // 20 (l0 k) + 60 (l1 w*20+k)
#define ROW2    16             // 4 (l0) + 12 (l1 w*4+k)
#define ROW1    4              // 1 (l0) + 3 (l1 w)
#define T3_OFF  0
#define T2_OFF  (N_CUBIC * ROW3)            // 13200
#define T1_OFF  (T2_OFF + N_QUAD * ROW2)    // 13920
#define TBL_TOTAL (T1_OFF + ELL * ROW1)     // 13956 floats = 55824 B

// ---------------------------------------------------------------------------
// Kernel A: build symmetrized product-basis tables into d_ws.
// T3[m][j]: m = lex index of (a<=b<=c); j<20 -> l0 k=j;
//           j>=20 -> l1, w=(j-20)/20, k=(j-20)%20.
// Entry = sum of U over all DISTINCT permutations of (a,b,c) on the three
// symmetric (ELL) contraction indices.
// ---------------------------------------------------------------------------
__global__ void build_tables(const float* __restrict__ U1_l0,
                             const float* __restrict__ U2_l0,
                             const float* __restrict__ U3_l0,
                             const float* __restrict__ U1_l1,
                             const float* __restrict__ U2_l1,
                             const float* __restrict__ U3_l1,
                             float* __restrict__ tbl)
{
    int idx = blockIdx.x * blockDim.x + threadIdx.x;
    if (idx >= TBL_TOTAL) return;

    if (idx < T2_OFF) {
        // -------- cubic --------
        int m = idx / ROW3, j = idx % ROW3;
        int a = 0, b = 0, c = 0, cnt = 0;
        for (int ai = 0; ai < ELL; ++ai)
            for (int bi = ai; bi < ELL; ++bi)
                for (int ci = bi; ci < ELL; ++ci) {
                    if (cnt == m) { a = ai; b = bi; c = ci; }
                    ++cnt;
                }
        int P[6][3] = {{a,b,c},{a,c,b},{b,a,c},{b,c,a},{c,a,b},{c,b,a}};
        float s = 0.f;
        for (int t = 0; t < 6; ++t) {
            bool dup = false;
            for (int u = 0; u < t; ++u)
                if (P[u][0]==P[t][0] && P[u][1]==P[t][1] && P[u][2]==P[t][2]) { dup = true; break; }
            if (dup) continue;
            int p0 = P[t][0], p1 = P[t][1], p2 = P[t][2];
            if (j < K3) {
                s += U3_l0[((p0*ELL + p1)*ELL + p2)*K3 + j];
            } else {
                int j2 = j - K3; int w = j2 / K3; int k = j2 % K3;
                s += U3_l1[(((w*ELL + p0)*ELL + p1)*ELL + p2)*K3 + k];
            }
        }
        tbl[idx] = s;
    } else if (idx < T1_OFF) {
        // -------- quadratic --------
        int r = idx - T2_OFF;
        int p = r / ROW2, j = r % ROW2;
        int a = 0, b = 0, cnt = 0;
        for (int ai = 0; ai < ELL; ++ai)
            for (int bi = ai; bi < ELL; ++bi) {
                if (cnt == p) { a = ai; b = bi; }
                ++cnt;
            }
        float s = 0.f;
        for (int t = 0; t < 2; ++t) {
            if (t == 1 && a == b) break;          // no duplicate perm
            int p0 = (t == 0) ? a : b;
            int p1 = (t == 0) ? b : a;
            if (j < K2) {
                s += U2_l0[(p0*ELL + p1)*K2 + j];
            } else {
                int j2 = j - K2; int w = j2 / K2; int k = j2 % K2;
                s += U2_l1[((w*ELL + p0)*ELL + p1)*K2 + k];
            }
        }
        tbl[idx] = s;
    } else {
        // -------- linear --------
        int r = idx - T1_OFF;
        int i = r / ROW1, j = r % ROW1;
        float s;
        if (j == 0) s = U1_l0[i];                  // (ELL,1)
        else        s = U1_l1[(j - 1)*ELL + i];    // (3,ELL,1)
        tbl[idx] = s;
    }
}

// ---------------------------------------------------------------------------
// Kernel B: per (b,c) evaluate the symmetrized polynomial, then combine with
// on-the-fly weighted weights w~[b,k,c] = sum_e y[b,e] * w[e,k,c].
// acc[] is indexed ONLY by compile-time constants (rule #20: runtime-indexed
// register arrays spill to scratch). Runtime-indexed x reads go through LDS.
// ---------------------------------------------------------------------------
__global__ __launch_bounds__(C_DIM) void symcon_main(
    const float* __restrict__ x,  const float* __restrict__ y,
    const float* __restrict__ w1_l0, const float* __restrict__ w2_l0, const float* __restrict__ w3_l0,
    const float* __restrict__ w1_l1, const float* __restrict__ w2_l1, const float* __restrict__ w3_l1,
    const float* __restrict__ tbl, float* __restrict__ out)
{
    const int b = blockIdx.x;
    const int c = threadIdx.x;

    __shared__ float xs[ELL][C_DIM];
    {
        const float* xp = x + (size_t)(b*C_DIM + c)*ELL;
        #pragma unroll
        for (int i = 0; i < ELL; ++i) xs[i][c] = xp[i];
    }
    __syncthreads();

    float acc[100];
    #pragma unroll
    for (int j = 0; j < 100; ++j) acc[j] = 0.f;

    // ---- cubic monomials, lex order (a<=b2<=c2), matches table order ----
    {
        const float* row = tbl + T3_OFF;
        for (int a = 0; a < ELL; ++a) {
            float xa = xs[a][c];
            for (int b2 = a; b2 < ELL; ++b2) {
                float xab = xa * xs[b2][c];
                for (int c2 = b2; c2 < ELL; ++c2) {
                    float x3 = xab * xs[c2][c];
                    #pragma unroll
                    for (int j = 0; j < ROW3; ++j)
                        acc[j] = fmaf(row[j], x3, acc[j]);
                    row += ROW3;
                }
            }
        }
    }
    // ---- quadratic ----
    {
        const float* row = tbl + T2_OFF;
        for (int a = 0; a < ELL; ++a) {
            float xa = xs[a][c];
            for (int b2 = a; b2 < ELL; ++b2) {
                float x2 = xa * xs[b2][c];
                #pragma unroll
                for (int j = 0; j < ROW2; ++j)
                    acc[80 + j] = fmaf(row[j], x2, acc[80 + j]);
                row += ROW2;
            }
        }
    }
    // ---- linear ----
    {
        const float* row = tbl + T1_OFF;
        for (int i = 0; i < ELL; ++i) {
            float x1 = xs[i][c];
            #pragma unroll
            for (int j = 0; j < ROW1; ++j)
                acc[96 + j] = fmaf(row[j], x1, acc[96 + j]);
            row += ROW1;
        }
    }

    // ---- combine with per-element weights ----
    float yb[E_DIM];
    #pragma unroll
    for (int e = 0; e < E_DIM; ++e) yb[e] = y[b*E_DIM + e];

    float out0 = 0.f, o10 = 0.f, o11 = 0.f, o12 = 0.f;

    #pragma unroll
    for (int k = 0; k < K3; ++k) {
        float wt = 0.f;
        #pragma unroll
        for (int e = 0; e < E_DIM; ++e)
            wt = fmaf(yb[e], w3_l0[(e*K3 + k)*C_DIM + c], wt);
        out0 = fmaf(wt, acc[k], out0);
    }
    #pragma unroll
    for (int k = 0; k < K2; ++k) {
        float wt = 0.f;
        #pragma unroll
        for (int e = 0; e < E_DIM; ++e)
            wt = fmaf(yb[e], w2_l0[(e*K2 + k)*C_DIM + c], wt);
        out0 = fmaf(wt, acc[80 + k], out0);
    }
    {
        float wt = 0.f;
        #pragma unroll
        for (int e = 0; e < E_DIM; ++e)
            wt = fmaf(yb[e], w1_l0[e*C_DIM + c], wt);
        out0 = fmaf(wt, acc[96], out0);
    }

    #pragma unroll
    for (int k = 0; k < K3; ++k) {
        float wt = 0.f;
        #pragma unroll
        for (int e = 0; e < E_DIM; ++e)
            wt = fmaf(yb[e], w3_l1[(e*K3 + k)*C_DIM + c], wt);
        o10 = fmaf(wt, acc[20 + k], o10);
        o11 = fmaf(wt, acc[40 + k], o11);
        o12 = fmaf(wt, acc[60 + k], o12);
    }
    #pragma unroll
    for (int k = 0; k < K2; ++k) {
        float wt = 0.f;
        #pragma unroll
        for (int e = 0; e < E_DIM; ++e)
            wt = fmaf(yb[e], w2_l1[(e*K2 + k)*C_DIM + c], wt);
        o10 = fmaf(wt, acc[84 + k], o10);
        o11 = fmaf(wt, acc[88 + k], o11);
        o12 = fmaf(wt, acc[92 + k], o12);
    }
    {
        float wt = 0.f;
        #pragma unroll
        for (int e = 0; e < E_DIM; ++e)
            wt = fmaf(yb[e], w1_l1[e*C_DIM + c], wt);
        o10 = fmaf(wt, acc[97], o10);
        o11 = fmaf(wt, acc[98], o11);
        o12 = fmaf(wt, acc[99], o12);
    }

    out[b*C_DIM + c] = out0;
    float* o1 = out + B_DIM*C_DIM + (size_t)(b*C_DIM + c)*3;
    o1[0] = o10; o1[1] = o11; o1[2] = o12;
}

// ---------------------------------------------------------------------------
extern "C" void kernel_launch(void* const* d_in, const int* in_sizes, int n_in,
                              void* d_out, int out_size, void* d_ws, size_t ws_size,
                              hipStream_t stream)
{
    const float* x     = (const float*)d_in[0];
    const float* y     = (const float*)d_in[1];
    const float* U1_l0 = (const float*)d_in[2];
    const float* U2_l0 = (const float*)d_in[3];
    const float* U3_l0 = (const float*)d_in[4];
    const float* U1_l1 = (const float*)d_in[5];
    const float* U2_l1 = (const float*)d_in[6];
    const float* U3_l1 = (const float*)d_in[7];
    const float* w1_l0 = (const float*)d_in[8];
    const float* w2_l0 = (const float*)d_in[9];
    const float* w3_l0 = (const float*)d_in[10];
    const float* w1_l1 = (const float*)d_in[11];
    const float* w2_l1 = (const float*)d_in[12];
    const float* w3_l1 = (const float*)d_in[13];

    float* tbl  = (float*)d_ws;           // 55824 B used
    float* outp = (float*)d_out;

    build_tables<<<(TBL_TOTAL + 255)/256, 256, 0, stream>>>(
        U1_l0, U2_l0, U3_l0, U1_l1, U2_l1, U3_l1, tbl);

    symcon_main<<<B_DIM, C_DIM, 0, stream>>>(
        x, y, w1_l0, w2_l0, w3_l0, w1_l1, w2_l1, w3_l1, tbl, outp);
}